// Round 10
// baseline (293.468 us; speedup 1.0000x reference)
//
#include <hip/hip_runtime.h>
#include <stdint.h>
#include <math.h>

typedef __attribute__((ext_vector_type(8))) short short8;
typedef __attribute__((ext_vector_type(4))) float f32x4;

#define DEVI static __device__ __forceinline__

constexpr int D = 256;  // feature dim
constexpr float LOG2E = 1.4426950408889634f;
constexpr float LN2   = 0.6931471805599453f;

// ws layout (bytes)
constexpr size_t WS_EIMG  = 0;                   // 32 tiles x 8192 = 262144
constexpr size_t WS_ETERM = 262144;              // 512 f32
constexpr size_t WS_WMAX  = 264192;              // 256 blk x 512 col f32 = 512K
constexpr size_t WS_WSUM  = WS_WMAX + 524288;    // 512K
constexpr size_t WS_PART  = WS_WSUM + 524288;    // 128 f32

DEVI unsigned int f2bf(float f) {
  unsigned int u = __float_as_uint(f);
  return (u + 0x7fffu + ((u >> 16) & 1u)) >> 16;  // RNE f32->bf16 (finite)
}
DEVI float shflx(float v, int m) { return __shfl_xor(v, m, 64); }

// ---- prep: e -> A-fragment images (16-col tiles, scaled a*log2e) + eterm ----
// Tile t covers e-cols [16t, 16t+16). 16x16x32 A layout: frag s, lane (q,c):
// byte = t*8192 + s*1024 + (q*16+c)*16 holds granule g = s*4+q (k=8g..8g+8)
// of col c. Stored via byte(g,c) = t*8192 + (g>>2)*1024 + (g&3)*256 + c*16.
__global__ void prep_e(const float* __restrict__ e, const float* __restrict__ lsp,
                       char* __restrict__ eimg, float* __restrict__ eterm) {
  const int tile = blockIdx.x, t = threadIdx.x;
  const int c = t >> 4, o = t & 15;   // col in tile, 16-elem k-slot
  const int gc = tile * 16 + c;
  const float a = __expf(-2.0f * lsp[0]);
  const float sab = a * LOG2E;        // fold score scale into the image
  const float* s = e + (size_t)gc * D + o * 16;
  float sq = 0.0f;
  unsigned int w[8];
#pragma unroll
  for (int i = 0; i < 4; ++i) {
    float4 x = *(const float4*)(s + i * 4);
    sq += x.x * x.x + x.y * x.y + x.z * x.z + x.w * x.w;
    w[2 * i]     = f2bf(sab * x.x) | (f2bf(sab * x.y) << 16);
    w[2 * i + 1] = f2bf(sab * x.z) | (f2bf(sab * x.w) << 16);
  }
  sq += shflx(sq, 1); sq += shflx(sq, 2);
  sq += shflx(sq, 4); sq += shflx(sq, 8);   // 16-lane col group
  char* base = eimg + (size_t)tile * 8192;
#pragma unroll
  for (int gg = 0; gg < 2; ++gg) {
    int g = 2 * o + gg;
    uint4 pk;
    pk.x = w[4 * gg]; pk.y = w[4 * gg + 1];
    pk.z = w[4 * gg + 2]; pk.w = w[4 * gg + 3];
    *(uint4*)(base + (g >> 2) * 1024 + (g & 3) * 256 + c * 16) = pk;
  }
  if (o == 0) eterm[gc] = -0.5f * a * sq;   // natural-log units
}

// ---- main: 256 blocks x 1024 thr (16 waves, 1 block/CU, 4 waves/SIMD).
// Wave w holds e-cols {16w..16w+15} u {256+16w..} as A0/A1 (64 VGPR).
// Block streams 256 z-rows in 8 chunks of 32 via reg->LDS staging
// (2-chunk-lookahead issue, 1-ahead commit, 2 buffers). 16x16x32 MFMA:
// B = z-rows; C: lane&15 = z-row, (lane>>4)*4+j = e-col -> per-lane running
// (mx, sm[4]) per col-group, cross-lane reduce once at the end. ----
__global__ __launch_bounds__(1024, 4)
void lse_main(const float* __restrict__ z, const char* __restrict__ eimg,
              const float* __restrict__ lsp, float* __restrict__ wmax,
              float* __restrict__ wsum) {
  __shared__ char  zbuf[2][16384];   // [buf][32 rows x 512B], granule-swizzled
  __shared__ float ztm[2][32];       // zterm (log2 units)

  const int tid = threadIdx.x;
  const int wid = tid >> 6, lane = tid & 63;
  const int l15 = lane & 15;   // B col = z-row slot; C col
  const int q   = lane >> 4;   // k-quarter of frags; C row-group
  const int n_st = tid >> 5;   // staging: chunk-local z-row 0..31
  const int g_st = tid & 31;   // staging: 16B granule (8 f32)
  const int bx = blockIdx.x;
  const float a = __expf(-2.0f * lsp[0]);
  const float ztf = -0.5f * a * LOG2E;
  const float* zrow = z + ((size_t)bx * 256 + n_st) * D + g_st * 8;

  float4 sA0, sA1, sB0, sB1;   // two staging reg sets (issue 2 chunks ahead)
  auto ISSUE_A = [&](int c) {
    const float* src = zrow + (size_t)(c * 32) * D;
    sA0 = *(const float4*)(src); sA1 = *(const float4*)(src + 4);
  };
  auto ISSUE_B = [&](int c) {
    const float* src = zrow + (size_t)(c * 32) * D;
    sB0 = *(const float4*)(src); sB1 = *(const float4*)(src + 4);
  };
  auto COMMIT = [&](int buf, float4 x0, float4 x1) {
    float sq = x0.x * x0.x + x0.y * x0.y + x0.z * x0.z + x0.w * x0.w +
               x1.x * x1.x + x1.y * x1.y + x1.z * x1.z + x1.w * x1.w;
    sq += shflx(sq, 1); sq += shflx(sq, 2); sq += shflx(sq, 4);
    sq += shflx(sq, 8); sq += shflx(sq, 16);   // 32 threads per row
    uint4 pk;
    pk.x = f2bf(x0.x) | (f2bf(x0.y) << 16);
    pk.y = f2bf(x0.z) | (f2bf(x0.w) << 16);
    pk.z = f2bf(x1.x) | (f2bf(x1.y) << 16);
    pk.w = f2bf(x1.z) | (f2bf(x1.w) << 16);
    *(uint4*)(&zbuf[buf][0] + n_st * 512 + ((g_st ^ n_st) * 16)) = pk;
    if (g_st == 0) ztm[buf][n_st] = ztf * sq;
  };

  // prologue: issue chunk0, load resident A-frags, commit chunk0, issue chunk1
  ISSUE_A(0);
  short8 A0[8], A1[8];
#pragma unroll
  for (int s = 0; s < 8; ++s) {
    A0[s] = *(const short8*)(eimg + (size_t)wid * 8192 + s * 1024 + lane * 16);
    A1[s] = *(const short8*)(eimg + (size_t)(wid + 16) * 8192 + s * 1024 + lane * 16);
  }
  COMMIT(0, sA0, sA1);
  ISSUE_B(1);
  __syncthreads();

  float mx0 = -1e30f, mx1 = -1e30f;
  float s0[4] = {0.f, 0.f, 0.f, 0.f}, s1[4] = {0.f, 0.f, 0.f, 0.f};

#pragma unroll
  for (int c = 0; c < 8; ++c) {
    const int cur = c & 1;
    // issue chunk c+2 into the set freed by last iteration's commit
    if (c + 2 < 8) { if ((c & 1) == 0) ISSUE_A(c + 2); else ISSUE_B(c + 2); }

    const char* bp = &zbuf[cur][0];
#pragma unroll
    for (int gr = 0; gr < 2; ++gr) {
      const int row = gr * 16 + l15;          // B: z-row in chunk
      const int rbase = row * 512;
      f32x4 a0 = {0.f, 0.f, 0.f, 0.f}, a1 = {0.f, 0.f, 0.f, 0.f};
#pragma unroll
      for (int s = 0; s < 8; ++s) {
        const int g = s * 4 + q;              // k granule for this lane
        short8 B = *(const short8*)(bp + rbase + ((g ^ row) * 16));
        a0 = __builtin_amdgcn_mfma_f32_16x16x32_bf16(A0[s], B, a0, 0, 0, 0);
        a1 = __builtin_amdgcn_mfma_f32_16x16x32_bf16(A1[s], B, a1, 0, 0, 0);
      }
      // online update: lane's z-row = c*32 + row; 4 e-cols per group
      const float zt = ztm[cur][row];
      float v0 = fmaxf(fmaxf(a0[0], a0[1]), fmaxf(a0[2], a0[3])) + zt;
      float v1 = fmaxf(fmaxf(a1[0], a1[1]), fmaxf(a1[2], a1[3])) + zt;
      float nm0 = fmaxf(mx0, v0), nm1 = fmaxf(mx1, v1);
      float sc0 = exp2f(mx0 - nm0), sc1 = exp2f(mx1 - nm1);
      const float t0 = zt - nm0, t1 = zt - nm1;
#pragma unroll
      for (int j = 0; j < 4; ++j) {
        s0[j] = s0[j] * sc0 + exp2f(a0[j] + t0);
        s1[j] = s1[j] * sc1 + exp2f(a1[j] + t1);
      }
      mx0 = nm0; mx1 = nm1;
    }

    if (c + 1 < 8) {
      if ((c & 1) == 0) COMMIT(cur ^ 1, sB0, sB1);   // chunk c+1 from set B
      else              COMMIT(cur ^ 1, sA0, sA1);   // chunk c+1 from set A
      __syncthreads();   // commit visible; all reads of buf[cur] done
    }
  }

  // final cross-lane reduction over the 16 z-row slots (lane bits 0..3)
  float M0 = mx0, M1 = mx1;
  M0 = fmaxf(M0, shflx(M0, 1)); M0 = fmaxf(M0, shflx(M0, 2));
  M0 = fmaxf(M0, shflx(M0, 4)); M0 = fmaxf(M0, shflx(M0, 8));
  M1 = fmaxf(M1, shflx(M1, 1)); M1 = fmaxf(M1, shflx(M1, 2));
  M1 = fmaxf(M1, shflx(M1, 4)); M1 = fmaxf(M1, shflx(M1, 8));
  const float c0 = exp2f(mx0 - M0), c1 = exp2f(mx1 - M1);
#pragma unroll
  for (int j = 0; j < 4; ++j) {
    float u0 = s0[j] * c0, u1 = s1[j] * c1;
    u0 += shflx(u0, 1); u0 += shflx(u0, 2); u0 += shflx(u0, 4); u0 += shflx(u0, 8);
    u1 += shflx(u1, 1); u1 += shflx(u1, 2); u1 += shflx(u1, 4); u1 += shflx(u1, 8);
    s0[j] = u0; s1[j] = u1;
  }
  if (l15 == 0) {   // lanes q=0..3 each write their 4 cols x 2 groups
#pragma unroll
    for (int j = 0; j < 4; ++j) {
      const int col = wid * 16 + q * 4 + j;
      wmax[(size_t)bx * 512 + col] = M0;          // log2 domain
      wsum[(size_t)bx * 512 + col] = s0[j];
      wmax[(size_t)bx * 512 + 256 + col] = M1;
      wsum[(size_t)bx * 512 + 256 + col] = s1[j];
    }
  }
}

// ---- merge the 2 main-blocks of each 512-row b-block, add eterm, reduce ----
__global__ void merge_b(const float* __restrict__ wmax, const float* __restrict__ wsum,
                        const float* __restrict__ eterm, float* __restrict__ partial) {
  __shared__ float sh[512];
  const int b = blockIdx.x, t = threadIdx.x;
  float m0 = wmax[(size_t)(2 * b) * 512 + t];
  float m1 = wmax[(size_t)(2 * b + 1) * 512 + t];
  float s0 = wsum[(size_t)(2 * b) * 512 + t];
  float s1 = wsum[(size_t)(2 * b + 1) * 512 + t];
  float nm = fmaxf(m0, m1);
  float s = s0 * exp2f(m0 - nm) + s1 * exp2f(m1 - nm);
  sh[t] = LN2 * (nm + log2f(s)) + eterm[t];   // back to e-units
  __syncthreads();
  for (int st = 256; st > 0; st >>= 1) {
    if (t < st) sh[t] += sh[t + st];
    __syncthreads();
  }
  if (t == 0) partial[b] = sh[0];
}

__global__ void final_k(const float* __restrict__ partial,
                        const float* __restrict__ lsp, float* __restrict__ out) {
  __shared__ float sh[128];
  const int t = threadIdx.x;
  sh[t] = partial[t];
  __syncthreads();
  for (int st = 64; st > 0; st >>= 1) {
    if (t < st) sh[t] += sh[t + st];
    __syncthreads();
  }
  if (t == 0) {
    float ls = lsp[0];
    out[0] = -sh[0] / 65536.0f + 128.0f * (2.0f * ls - 1.0f) + logf(512.0f);
  }
}

extern "C" void kernel_launch(void* const* d_in, const int* in_sizes, int n_in,
                              void* d_out, int out_size, void* d_ws, size_t ws_size,
                              hipStream_t stream) {
  const float* z   = (const float*)d_in[0];
  const float* e   = (const float*)d_in[1];
  const float* lsp = (const float*)d_in[2];
  float* out = (float*)d_out;
  char* ws = (char*)d_ws;
  char*  eimg    = ws + WS_EIMG;
  float* eterm   = (float*)(ws + WS_ETERM);
  float* wmax    = (float*)(ws + WS_WMAX);
  float* wsum    = (float*)(ws + WS_WSUM);
  float* partial = (float*)(ws + WS_PART);

  prep_e<<<dim3(32), dim3(256), 0, stream>>>(e, lsp, eimg, eterm);
  lse_main<<<dim3(256), dim3(1024), 0, stream>>>(z, eimg, lsp, wmax, wsum);
  merge_b<<<dim3(128), dim3(512), 0, stream>>>(wmax, wsum, eterm, partial);
  final_k<<<dim3(1), dim3(128), 0, stream>>>(partial, lsp, out);
}

// Round 11
// 45.034 us; speedup vs baseline: 6.5166x; 6.5166x over previous
//
#include <hip/hip_runtime.h>
#include <stdint.h>
#include <math.h>

typedef __attribute__((ext_vector_type(8))) short short8;
typedef __attribute__((ext_vector_type(16))) float f32x16;

#define DEVI static __device__ __forceinline__

constexpr int D = 256;  // feature dim
constexpr float LOG2E = 1.4426950408889634f;
constexpr float LN2   = 0.6931471805599453f;

// ws layout (bytes)
constexpr size_t WS_EIMG  = 0;                   // 16 tiles x 16384 = 262144
constexpr size_t WS_ETERM = 262144;              // 512 f32
constexpr size_t WS_WMAX  = 264192;              // 1024 blk x 512 col = 2 MB
constexpr size_t WS_WSUM  = WS_WMAX + 2097152;   // 2 MB
constexpr size_t WS_PART  = WS_WSUM + 2097152;   // 128 f32

DEVI unsigned int f2bf(float f) {
  unsigned int u = __float_as_uint(f);
  return (u + 0x7fffu + ((u >> 16) & 1u)) >> 16;  // RNE f32->bf16 (finite)
}
DEVI float shflx(float v, int m) { return __shfl_xor(v, m, 64); }

// ---- prep: e -> B-fragment tile images (32-col tiles, scaled a*log2e) ----
// Tile t covers e-cols [32t, 32t+32). B-frag for k-step s, lane (hi,c):
//   byte = t*16384 + s*1024 + (hi*32 + c)*16 holds granule g = 2s+hi
//   (k in [8g, 8g+8)) of col c.   (R6-validated layout, absmax 0)
__global__ void prep_e(const float* __restrict__ e, const float* __restrict__ lsp,
                       char* __restrict__ eimg, float* __restrict__ eterm) {
  const int et = blockIdx.x, t = threadIdx.x;
  const int c = t >> 3, o = t & 7;   // col in tile, octant of 256 k
  const int gc = et * 32 + c;
  const float a = __expf(-2.0f * lsp[0]);
  const float sab = a * LOG2E;       // fold score scale into the image
  const float* s = e + (size_t)gc * D + o * 32;
  float sq = 0.0f;
  unsigned int w[16];
#pragma unroll
  for (int i = 0; i < 8; ++i) {
    float4 x = *(const float4*)(s + i * 4);
    sq += x.x * x.x + x.y * x.y + x.z * x.z + x.w * x.w;
    w[2 * i]     = f2bf(sab * x.x) | (f2bf(sab * x.y) << 16);
    w[2 * i + 1] = f2bf(sab * x.z) | (f2bf(sab * x.w) << 16);
  }
  sq += shflx(sq, 1); sq += shflx(sq, 2); sq += shflx(sq, 4);  // 8-lane group
  char* base = eimg + (size_t)et * 16384;
#pragma unroll
  for (int i = 0; i < 4; ++i) {
    int g = o * 4 + i;  // 16B k-granule
    int phys = (g >> 1) * 1024 + (g & 1) * 512 + c * 16;
    uint4 pk; pk.x = w[4 * i]; pk.y = w[4 * i + 1];
    pk.z = w[4 * i + 2]; pk.w = w[4 * i + 3];
    *(uint4*)(base + phys) = pk;
  }
  if (o == 0) eterm[gc] = -0.5f * a * sq;   // natural-log units
}

// ---- main: 1024 blocks x 512 thr (8 waves; 2 blocks/CU, 4 waves/SIMD).
// Block stages its 64 z-rows once into LDS (bf16, XOR-swizzled) -> ONE
// barrier -> each wave independently computes all 64 rows x its 64-col
// e-strip over K=256 (acc[2][2] f32x16, 4 MFMA chains; A=z from LDS,
// B=e frags from L2-resident image). Exact single-pass LSE epilogue. ----
__global__ __launch_bounds__(512, 4)
void lse_main(const float* __restrict__ z, const char* __restrict__ eimg,
              const float* __restrict__ lsp, float* __restrict__ wmax,
              float* __restrict__ wsum) {
  __shared__ char  zbuf[32768];   // 64 rows x 512B, granule-XOR-swizzled
  __shared__ float ztm[64];       // z row-norm terms (log2 units)

  const int tid = threadIdx.x;
  const int wid = tid >> 6, lane = tid & 63;
  const int l31 = lane & 31;   // A row (z-row) / B col (e-col)
  const int hi  = lane >> 5;   // k-half of frags; C row-group bit
  const int bx = blockIdx.x;
  const float a = __expf(-2.0f * lsp[0]);
  const float ztf = -0.5f * a * LOG2E;

  // ---- stage 64 z-rows: thread = (row = tid>>3, octant o = tid&7) ----
  {
    const int row = tid >> 3, o = tid & 7;
    const float* src = z + ((size_t)bx * 64 + row) * D + o * 32;
    float sq = 0.0f;
#pragma unroll
    for (int i = 0; i < 4; ++i) {   // 4 granule-pairs = 8 f32 each
      float4 x0 = *(const float4*)(src + i * 8);
      float4 x1 = *(const float4*)(src + i * 8 + 4);
      sq += x0.x * x0.x + x0.y * x0.y + x0.z * x0.z + x0.w * x0.w +
            x1.x * x1.x + x1.y * x1.y + x1.z * x1.z + x1.w * x1.w;
      uint4 pk;
      pk.x = f2bf(x0.x) | (f2bf(x0.y) << 16);
      pk.y = f2bf(x0.z) | (f2bf(x0.w) << 16);
      pk.z = f2bf(x1.x) | (f2bf(x1.y) << 16);
      pk.w = f2bf(x1.z) | (f2bf(x1.w) << 16);
      const int g = o * 4 + i;      // this thread's 16B k-granule
      *(uint4*)(zbuf + row * 512 + ((g ^ (row & 31)) * 16)) = pk;
    }
    sq += shflx(sq, 1); sq += shflx(sq, 2); sq += shflx(sq, 4);  // 8 thr/row
    if (o == 0) ztm[row] = ztf * sq;
  }
  __syncthreads();   // the ONLY barrier — waves are independent after this

  // ---- K=256 single pass: wave's strip = e-cols [wid*64, wid*64+64) ----
  f32x16 acc00, acc01, acc10, acc11;   // [rowgroup][colgroup]
#pragma unroll
  for (int i = 0; i < 16; ++i) { acc00[i] = 0.f; acc01[i] = 0.f;
                                 acc10[i] = 0.f; acc11[i] = 0.f; }
  const char* eb0 = eimg + (size_t)(2 * wid) * 16384 + lane * 16;
  const char* ab0 = zbuf + l31 * 512;          // rows 0..31
  const char* ab1 = zbuf + (32 + l31) * 512;   // rows 32..63 (same XOR key)
#pragma unroll
  for (int s = 0; s < 16; ++s) {
    const int g = 2 * s + hi;
    const int key = (g ^ l31) * 16;
    short8 A0 = *(const short8*)(ab0 + key);
    short8 A1 = *(const short8*)(ab1 + key);
    short8 B0 = *(const short8*)(eb0 + s * 1024);
    short8 B1 = *(const short8*)(eb0 + 16384 + s * 1024);
    acc00 = __builtin_amdgcn_mfma_f32_32x32x16_bf16(A0, B0, acc00, 0, 0, 0);
    acc01 = __builtin_amdgcn_mfma_f32_32x32x16_bf16(A0, B1, acc01, 0, 0, 0);
    acc10 = __builtin_amdgcn_mfma_f32_32x32x16_bf16(A1, B0, acc10, 0, 0, 0);
    acc11 = __builtin_amdgcn_mfma_f32_32x32x16_bf16(A1, B1, acc11, 0, 0, 0);
  }

  // ---- epilogue: add z terms; exact LSE partial per e-col ----
  // C layout: col = l31 (+cg*32), row = rg*32 + (r&3) + 8*(r>>2) + 4*hi.
#pragma unroll
  for (int r = 0; r < 16; ++r) {
    const int rr = (r & 3) + 8 * (r >> 2) + 4 * hi;
    const float zt0 = ztm[rr];        // broadcast reads (conflict-free)
    const float zt1 = ztm[32 + rr];
    acc00[r] += zt0; acc01[r] += zt0;
    acc10[r] += zt1; acc11[r] += zt1;
  }
  float mx0 = -1e30f, mx1 = -1e30f;
#pragma unroll
  for (int r = 0; r < 16; ++r) {
    mx0 = fmaxf(mx0, fmaxf(acc00[r], acc10[r]));
    mx1 = fmaxf(mx1, fmaxf(acc01[r], acc11[r]));
  }
  mx0 = fmaxf(mx0, shflx(mx0, 32));   // other 32 rows live in partner lane
  mx1 = fmaxf(mx1, shflx(mx1, 32));
  float sm0 = 0.f, sm1 = 0.f;
#pragma unroll
  for (int r = 0; r < 16; ++r) {
    sm0 += exp2f(acc00[r] - mx0) + exp2f(acc10[r] - mx0);
    sm1 += exp2f(acc01[r] - mx1) + exp2f(acc11[r] - mx1);
  }
  sm0 += shflx(sm0, 32);
  sm1 += shflx(sm1, 32);
  if (hi == 0) {   // both halves hold the merged result; lane<32 writes
    const int col = wid * 64 + l31;
    wmax[(size_t)bx * 512 + col] = mx0;        // log2 domain
    wsum[(size_t)bx * 512 + col] = sm0;
    wmax[(size_t)bx * 512 + 32 + col] = mx1;
    wsum[(size_t)bx * 512 + 32 + col] = sm1;
  }
}

// ---- merge the 8 row-blocks of each 512-row window, add eterm, reduce ----
__global__ void merge_b(const float* __restrict__ wmax, const float* __restrict__ wsum,
                        const float* __restrict__ eterm, float* __restrict__ partial) {
  __shared__ float sh[512];
  const int b = blockIdx.x, t = threadIdx.x;
  float m[8];
  float nm = -1e30f;
#pragma unroll
  for (int i = 0; i < 8; ++i) {
    m[i] = wmax[(size_t)(8 * b + i) * 512 + t];
    nm = fmaxf(nm, m[i]);
  }
  float s = 0.0f;
#pragma unroll
  for (int i = 0; i < 8; ++i)
    s += wsum[(size_t)(8 * b + i) * 512 + t] * exp2f(m[i] - nm);
  sh[t] = LN2 * (nm + log2f(s)) + eterm[t];   // back to natural units
  __syncthreads();
  for (int st = 256; st > 0; st >>= 1) {
    if (t < st) sh[t] += sh[t + st];
    __syncthreads();
  }
  if (t == 0) partial[b] = sh[0];
}

__global__ void final_k(const float* __restrict__ partial,
                        const float* __restrict__ lsp, float* __restrict__ out) {
  __shared__ float sh[128];
  const int t = threadIdx.x;
  sh[t] = partial[t];
  __syncthreads();
  for (int st = 64; st > 0; st >>= 1) {
    if (t < st) sh[t] += sh[t + st];
    __syncthreads();
  }
  if (t == 0) {
    float ls = lsp[0];
    out[0] = -sh[0] / 65536.0f + 128.0f * (2.0f * ls - 1.0f) + logf(512.0f);
  }
}

extern "C" void kernel_launch(void* const* d_in, const int* in_sizes, int n_in,
                              void* d_out, int out_size, void* d_ws, size_t ws_size,
                              hipStream_t stream) {
  const float* z   = (const float*)d_in[0];
  const float* e   = (const float*)d_in[1];
  const float* lsp = (const float*)d_in[2];
  float* out = (float*)d_out;
  char* ws = (char*)d_ws;
  char*  eimg    = ws + WS_EIMG;
  float* eterm   = (float*)(ws + WS_ETERM);
  float* wmax    = (float*)(ws + WS_WMAX);
  float* wsum    = (float*)(ws + WS_WSUM);
  float* partial = (float*)(ws + WS_PART);

  prep_e<<<dim3(16), dim3(256), 0, stream>>>(e, lsp, eimg, eterm);
  lse_main<<<dim3(1024), dim3(512), 0, stream>>>(z, eimg, lsp, wmax, wsum);
  merge_b<<<dim3(128), dim3(512), 0, stream>>>(wmax, wsum, eterm, partial);
  final_k<<<dim3(1), dim3(128), 0, stream>>>(partial, lsp, out);
}